// Round 2
// baseline (411.054 us; speedup 1.0000x reference)
//
#include <hip/hip_runtime.h>

// CBOW negative-sampling loss on MI355X.
// Sizes fixed by the reference.
#define BATCH 16384
#define CTX 10
#define EMB 256             // 64 float4 per row
#define TASKS (BATCH * 2)   // pos + neg side per batch element
#define BLOCKS (TASKS / 4)  // 4 waves (tasks) per 256-thread block = 8192

// One wave (64 lanes) per (batch, side) task. lane i owns float4 slice
// [4i, 4i+3] of the 256-dim embedding. 4 waves per 256-thread block.
__global__ __launch_bounds__(256) void cbow_loss_kernel(
    const int* __restrict__ pos_u, const int* __restrict__ pos_w,
    const int* __restrict__ neg_u, const int* __restrict__ neg_w,
    const float* __restrict__ u_weight, const float* __restrict__ w_weight,
    float* __restrict__ out)
{
    __shared__ float wave_sum[4];

    const int lane = threadIdx.x & 63;
    const int wave = threadIdx.x >> 6;
    const int task = blockIdx.x * 4 + wave;   // 0 .. TASKS-1 exactly
    const int b    = task >> 1;
    const int neg  = task & 1;

    const int* __restrict__ uidx = neg ? neg_u : pos_u;
    const int* __restrict__ widx = neg ? neg_w : pos_w;

    const float4* __restrict__ U = (const float4*)u_weight;  // row stride 64
    const float4* __restrict__ W = (const float4*)w_weight;

    // Sum of CTX gathered context rows (this wave's float4 slice).
    float4 acc = make_float4(0.f, 0.f, 0.f, 0.f);
    const int* __restrict__ rowp = uidx + b * CTX;
#pragma unroll
    for (int c = 0; c < CTX; ++c) {
        const int r = rowp[c];                       // wave-uniform index
        const float4 v = U[(size_t)r * 64 + lane];   // coalesced 1KB row burst
        acc.x += v.x; acc.y += v.y; acc.z += v.z; acc.w += v.w;
    }

    const int wr = widx[b];
    const float4 wv = W[(size_t)wr * 64 + lane];

    float p = acc.x * wv.x + acc.y * wv.y + acc.z * wv.z + acc.w * wv.w;

    // 64-lane butterfly reduction of the dot product.
#pragma unroll
    for (int m = 32; m >= 1; m >>= 1)
        p += __shfl_xor(p, m, 64);

    const float x = neg ? -p : p;
    // numerically stable log_sigmoid: min(x,0) - log1p(exp(-|x|))
    const float ls = fminf(x, 0.f) - log1pf(expf(-fabsf(x)));

    if (lane == 0) wave_sum[wave] = -ls;   // loss = -(sum of scores)
    __syncthreads();

    if (threadIdx.x == 0) {
        atomicAdd(out, wave_sum[0] + wave_sum[1] + wave_sum[2] + wave_sum[3]);
    }
}

extern "C" void kernel_launch(void* const* d_in, const int* in_sizes, int n_in,
                              void* d_out, int out_size, void* d_ws, size_t ws_size,
                              hipStream_t stream) {
    const int*   pos_u    = (const int*)d_in[0];
    const int*   pos_w    = (const int*)d_in[1];
    const int*   neg_u    = (const int*)d_in[2];
    const int*   neg_w    = (const int*)d_in[3];
    const float* u_weight = (const float*)d_in[4];
    const float* w_weight = (const float*)d_in[5];
    float*       out      = (float*)d_out;

    // d_out is poisoned to 0xAA before every run; zero it (async, capture-safe).
    hipMemsetAsync(out, 0, sizeof(float), stream);

    cbow_loss_kernel<<<BLOCKS, 256, 0, stream>>>(
        pos_u, pos_w, neg_u, neg_w, u_weight, w_weight, out);
}

// Round 3
// 375.217 us; speedup vs baseline: 1.0955x; 1.0955x over previous
//
#include <hip/hip_runtime.h>

// CBOW negative-sampling loss on MI355X.
#define BATCH 16384
#define CTX 10
#define EMB 256             // 64 float4 per row
#define TASKS (BATCH * 2)   // pos + neg side per batch element
#define T 4                 // tasks per wave (MLP amplifier)
#define WAVES 4             // waves per block
#define BLOCKS (TASKS / (T * WAVES))  // 2048

// One wave handles T tasks. lane i owns float4 slice [4i,4i+3] of the
// 256-dim embedding. Indices fetched cooperatively (lanes 0..CTX), then
// broadcast via shfl, so each task costs 1 index-load instruction and the
// index latency of all T tasks overlaps; 11*T independent 1KB row gathers
// per wave keep the memory queues full.
__global__ __launch_bounds__(256) void cbow_loss_kernel(
    const int* __restrict__ pos_u, const int* __restrict__ pos_w,
    const int* __restrict__ neg_u, const int* __restrict__ neg_w,
    const float* __restrict__ u_weight, const float* __restrict__ w_weight,
    float* __restrict__ out)
{
    __shared__ float wave_sum[WAVES];

    const int lane  = threadIdx.x & 63;
    const int wave  = threadIdx.x >> 6;
    const int task0 = (blockIdx.x * WAVES + wave) * T;

    const float4* __restrict__ U = (const float4*)u_weight;  // row stride 64
    const float4* __restrict__ W = (const float4*)w_weight;

    // Phase 0: cooperative index loads for all T tasks (issued back-to-back,
    // latencies overlap). lane c<CTX -> u index c; lane==CTX -> w index.
    int iv[T];
#pragma unroll
    for (int t = 0; t < T; ++t) {
        const int task = task0 + t;
        const int b    = task >> 1;
        const int neg  = task & 1;
        const int* __restrict__ ui = neg ? neg_u : pos_u;
        const int* __restrict__ wi = neg ? neg_w : pos_w;
        int v = 0;
        if (lane <= CTX) v = (lane < CTX) ? ui[b * CTX + lane] : wi[b];
        iv[t] = v;
    }

    // Phase 1: per task, broadcast indices and issue 11 independent 1KB
    // row gathers; accumulate, dot, 64-lane butterfly, log-sigmoid.
    float lsum = 0.f;
#pragma unroll
    for (int t = 0; t < T; ++t) {
        const int neg = (task0 + t) & 1;

        const int wr = __shfl(iv[t], CTX, 64);
        const float4 wv = W[(size_t)wr * 64 + lane];

        float4 acc = make_float4(0.f, 0.f, 0.f, 0.f);
#pragma unroll
        for (int c = 0; c < CTX; ++c) {
            const int r = __shfl(iv[t], c, 64);
            const float4 v = U[(size_t)r * 64 + lane];
            acc.x += v.x; acc.y += v.y; acc.z += v.z; acc.w += v.w;
        }

        float p = acc.x * wv.x + acc.y * wv.y + acc.z * wv.z + acc.w * wv.w;
#pragma unroll
        for (int m = 32; m >= 1; m >>= 1)
            p += __shfl_xor(p, m, 64);

        const float x = neg ? -p : p;
        lsum += fminf(x, 0.f) - log1pf(expf(-fabsf(x)));  // log_sigmoid
    }

    if (lane == 0) wave_sum[wave] = -lsum;   // loss = -(sum of scores)
    __syncthreads();

    if (threadIdx.x == 0) {
        float s = 0.f;
#pragma unroll
        for (int w = 0; w < WAVES; ++w) s += wave_sum[w];
        atomicAdd(out, s);
    }
}

extern "C" void kernel_launch(void* const* d_in, const int* in_sizes, int n_in,
                              void* d_out, int out_size, void* d_ws, size_t ws_size,
                              hipStream_t stream) {
    const int*   pos_u    = (const int*)d_in[0];
    const int*   pos_w    = (const int*)d_in[1];
    const int*   neg_u    = (const int*)d_in[2];
    const int*   neg_w    = (const int*)d_in[3];
    const float* u_weight = (const float*)d_in[4];
    const float* w_weight = (const float*)d_in[5];
    float*       out      = (float*)d_out;

    // d_out is poisoned to 0xAA before every run; zero it (async, capture-safe).
    hipMemsetAsync(out, 0, sizeof(float), stream);

    cbow_loss_kernel<<<BLOCKS, 256, 0, stream>>>(
        pos_u, pos_w, neg_u, neg_w, u_weight, w_weight, out);
}